// Round 17
// baseline (26.992 us; speedup 1.0000x reference)
//
#include <hip/hip_runtime.h>

// Chamfer min-matching loss, B=8, P=4096, D=2, fp32 — exact NN via x-sorted
// rank-window scan + wave-cooperative rescue.
// Kernel 1 (xSort, 16 blocks x 512 thr): counting-sort each (batch,side) by
//   x-bin: one coalesced read into NAMED registers, LDS histogram + shfl scan,
//   LDS scatter, coalesced write-out. 512 threads halve the serial depth (R16).
// Kernel 2 (winSearch, 256 blocks): per-lane rank r0 from global BS lookup;
//   block-reduce [min(w0), max(w0)+256) band; stage ONLY the band (~4 KB vs
//   36 KB). Fixed 256-candidate window scan + certificate; uncertified lanes
//   (incl. band-clamped ones) rescued by wave-cooperative full scan of the
//   sorted target in GLOBAL (L2-hot, coalesced).
// R12: sorted queries -> conflict-free scan. R13: no per-lane expansion loops.
// R16: random global scatter was the sort cost; staging was the search cost.

#define NB    8
#define NP    4096
#define XBINS 2048
#define W     0.0048828125f      // 10 / 2048
#define XMIN  -5.0f
#define INVW  204.8f
#define BSSTR (XBINS + 4)        // u32 stride, 16B-aligned
#define WH    128                // half-window (256 candidates)
#define BANDMAX 2048             // max staged band (16 KB)

__device__ __forceinline__ int xbin(float x) {
    int i = (int)((x - XMIN) * INVW);
    return i < 0 ? 0 : (i > XBINS - 1 ? XBINS - 1 : i);
}

#define FOREACH4(M) M(0) M(1) M(2) M(3)

// ---- Kernel 1: counting sort by x-bin, one block per (batch, side) ----
__global__ __launch_bounds__(512) void xSort(const float* __restrict__ pred,
                                             const float* __restrict__ gt,
                                             float2* __restrict__ P,      // [16][NP]
                                             unsigned* __restrict__ BS,   // [16][BSSTR]
                                             float* __restrict__ out) {
    __shared__ __align__(16) float2 sp[NP];     // 32 KB sorted staging
    __shared__ unsigned cnt[XBINS];             // 8 KB hist -> starts -> cursors
    __shared__ unsigned waveTot[8];

    int t = threadIdx.x;
    int s = blockIdx.x;                 // 0..15
    int b = s >> 1, side = s & 1;

    if (s == 0 && t == 0) *out = 0.0f;  // stream order: before winSearch atomics

    const float2* src = (const float2*)(side ? gt : pred) + (size_t)b * NP;
    float2*   dst = P  + (size_t)s * NP;
    unsigned* bs  = BS + (size_t)s * BSSTR;

#pragma unroll
    for (int i = 0; i < XBINS / 512; ++i) cnt[t + i * 512] = 0;
    __syncthreads();

    // one coalesced read into named registers + histogram (8 pts/thread)
    const float4* src4 = (const float4*)src;    // 2048 float4
#define DECLV(i) float4 v##i = src4[t + (i) * 512]; \
    atomicAdd(&cnt[xbin(v##i.x)], 1u); atomicAdd(&cnt[xbin(v##i.z)], 1u);
    FOREACH4(DECLV)
#undef DECLV
    __syncthreads();

    // exclusive scan over 2048 bins (4 bins/thread + shfl wave scan, 8 waves)
    unsigned local = cnt[t * 4] + cnt[t * 4 + 1] + cnt[t * 4 + 2] + cnt[t * 4 + 3];
    unsigned inc = local;
#pragma unroll
    for (int o = 1; o < 64; o <<= 1) {
        unsigned n = __shfl_up(inc, o, 64);
        if ((t & 63) >= o) inc += n;
    }
    if ((t & 63) == 63) waveTot[t >> 6] = inc;
    __syncthreads();
    unsigned wbase = 0;
#pragma unroll
    for (int w = 0; w < 8; ++w) if (w < (t >> 6)) wbase += waveTot[w];
    unsigned run = wbase + inc - local;
#pragma unroll
    for (int i = 0; i < 4; ++i) {
        unsigned c = cnt[t * 4 + i];
        cnt[t * 4 + i] = run;           // bin starts
        run += c;
    }
    __syncthreads();

    // publish starts (coalesced) BEFORE cursors mutate
    for (int i = t; i < XBINS; i += 512) bs[i] = cnt[i];
    __syncthreads();

    // scatter from registers into LDS sorted array (cheap random ds_write)
#define SCAT(i) { \
    unsigned p0 = atomicAdd(&cnt[xbin(v##i.x)], 1u); \
    sp[p0] = (float2){v##i.x, v##i.y}; \
    unsigned p1 = atomicAdd(&cnt[xbin(v##i.z)], 1u); \
    sp[p1] = (float2){v##i.z, v##i.w}; }
    FOREACH4(SCAT)
#undef SCAT
    __syncthreads();

    // coalesced write-out of the sorted array
    const float4* sp4 = (const float4*)sp;
    float4*       dst4 = (float4*)dst;
#pragma unroll
    for (int i = 0; i < 4; ++i) dst4[t + i * 512] = sp4[t + i * 512];
}

// ---- Kernel 2: banded window scan + wave-cooperative global rescue ----
__global__ __launch_bounds__(256) void winSearch(const float2* __restrict__ P,
                                                 const unsigned* __restrict__ BS,
                                                 float* __restrict__ out) {
    __shared__ __align__(16) float2 sp[BANDMAX];   // 16 KB staged band
    __shared__ int redmin[4], redmax[4];
    __shared__ float wsum[4];

    int t     = threadIdx.x;
    int bid   = blockIdx.x;        // 0..255
    int qs    = bid & 15;          // dir*8 + b
    int slice = bid >> 4;          // 0..15
    int b = qs & 7, dir = qs >> 3;

    int tgt = b * 2 + (1 - dir);   // sorted target side
    const float2*   tp = P  + (size_t)tgt * NP;
    const unsigned* bs = BS + (size_t)tgt * BSSTR;
    const float4*   tp4 = (const float4*)tp;

    // query from the SORTED query-side array (coalesced; order-invariant mean)
    const float2* qarr = P + (size_t)(b * 2 + dir) * NP;
    float2 q = qarr[slice * 256 + t];
    float qx = q.x, qy = q.y;

    // per-lane window start from global bin-start lookup (L2-hot)
    int r0 = (int)bs[xbin(qx)];
    int w0 = r0 - WH;
    if (w0 < 0) w0 = 0;
    if (w0 > NP - 2 * WH) w0 = NP - 2 * WH;
    w0 &= ~1;

    // block-reduce band = [min(w0), max(w0)+256)
    int mn = w0, mx = w0;
#pragma unroll
    for (int o = 32; o > 0; o >>= 1) {
        mn = min(mn, __shfl_xor(mn, o, 64));
        mx = max(mx, __shfl_xor(mx, o, 64));
    }
    int lane = t & 63, wv = t >> 6;
    if (lane == 0) { redmin[wv] = mn; redmax[wv] = mx; }
    __syncthreads();
    int lo = min(min(redmin[0], redmin[1]), min(redmin[2], redmin[3]));
    int hi = max(max(redmax[0], redmax[1]), max(redmax[2], redmax[3])) + 2 * WH;
    if (hi - lo > BANDMAX) hi = lo + BANDMAX;

    int w0c = w0;
    if (w0c > hi - 2 * WH) w0c = hi - 2 * WH;   // >= lo (hi >= lo + 2*WH)

    // stage only the band (typ. ~512 pts = 4 KB)
    int nf4 = (hi - lo) >> 1;
    float4* sp4w = (float4*)sp;
    for (int i = t; i < nf4; i += 256) sp4w[i] = tp4[(lo >> 1) + i];
    __syncthreads();

    // fixed 256-candidate window scan (conflict-free: lanes rank-adjacent)
    float best = 3.402823466e+38f;
    const float4* spc = (const float4*)sp;
    int base = (w0c - lo) >> 1;
#pragma unroll 8
    for (int k = 0; k < WH; ++k) {
        float4 v = spc[base + k];
        float dx0 = qx - v.x, dy0 = qy - v.y;
        float dx1 = qx - v.z, dy1 = qy - v.w;
        float d0 = fmaf(dx0, dx0, dy0 * dy0);
        float d1 = fmaf(dx1, dx1, dy1 * dy1);
        best = fminf(fminf(best, d0), d1);       // v_min3_f32
    }

    // certificate (bin-sorted: rank<w0c => x <= sp[w0c].x + W, mirrored)
    float lbL = (w0c > 0)           ? fmaxf(qx - sp[w0c - lo].x - W, 0.0f)                : 3.0e38f;
    float lbR = (w0c + 2 * WH < NP) ? fmaxf(sp[w0c + 2 * WH - 1 - lo].x - W - qx, 0.0f)   : 3.0e38f;
    bool uncert = (lbL * lbL < best) || (lbR * lbR < best);

    // wave-cooperative rescue: full exact scan of GLOBAL sorted target
    unsigned long long mask = __ballot(uncert);
    while (mask) {
        int l = __ffsll((long long)mask) - 1;
        mask &= mask - 1;
        float qlx = __shfl(qx, l, 64);
        float qly = __shfl(qy, l, 64);
        float rb = 3.402823466e+38f;
#pragma unroll 4
        for (int i = 0; i < 32; ++i) {          // 64 lanes x 32 f4 = all 4096
            float4 v = tp4[lane + i * 64];      // coalesced, L2-hot
            float dx0 = qlx - v.x, dy0 = qly - v.y;
            float dx1 = qlx - v.z, dy1 = qly - v.w;
            rb = fminf(rb, fmaf(dx0, dx0, dy0 * dy0));
            rb = fminf(rb, fmaf(dx1, dx1, dy1 * dy1));
        }
#pragma unroll
        for (int o = 32; o > 0; o >>= 1) rb = fminf(rb, __shfl_xor(rb, o, 64));
        if (lane == l) best = rb;
    }

    float v = sqrtf(fmaxf(best, 1e-12f));
#pragma unroll
    for (int o = 32; o > 0; o >>= 1) v += __shfl_down(v, o, 64);
    if (lane == 0) wsum[wv] = v;
    __syncthreads();
    if (t == 0)
        atomicAdd(out, ((wsum[0] + wsum[1]) + (wsum[2] + wsum[3])) *
                           (0.5f / (float)(NB * NP)));
}

extern "C" void kernel_launch(void* const* d_in, const int* in_sizes, int n_in,
                              void* d_out, int out_size, void* d_ws, size_t ws_size,
                              hipStream_t stream) {
    const float* pred = (const float*)d_in[0];
    const float* gt   = (const float*)d_in[1];
    float*       out  = (float*)d_out;

    float2*   P  = (float2*)d_ws;                       // 16 * 4096 * 8 B = 512 KB
    unsigned* BS = (unsigned*)(P + (size_t)16 * NP);    // 16 * 2052 * 4 B

    (void)in_sizes; (void)n_in; (void)out_size; (void)ws_size;

    xSort<<<16, 512, 0, stream>>>(pred, gt, P, BS, out);
    winSearch<<<256, 256, 0, stream>>>(P, BS, out);
}